// Round 5
// baseline (353.101 us; speedup 1.0000x reference)
//
#include <hip/hip_runtime.h>
#include <hip/hip_bf16.h>

#define B_   32
#define L_   2048
#define H_   768
#define W_   512
#define NC_  16
#define HH_  384                 // H/2
#define NWORDS (B_ * W_)         // 16384
#define NLOGITS (NWORDS * NC_)   // 262144

typedef __attribute__((ext_vector_type(8))) __bf16 bf16x8;
typedef __attribute__((ext_vector_type(4))) float floatx4;

static __device__ __forceinline__ unsigned short f2bf(float x) {
    union { float f; unsigned u; } v; v.f = x;
    unsigned r = v.u + 0x7FFF + ((v.u >> 16) & 1);   // RNE fp32->bf16
    return (unsigned short)(r >> 16);
}

// ---------------- K0: W1 [768][384] f32 -> w1t [384][768] bf16 (coalesced tiled transpose)
__global__ __launch_bounds__(256) void k_convert_w1(const float* __restrict__ W1,
                                                    unsigned short* __restrict__ w1t) {
    __shared__ unsigned short tile[64][65];
    const int k0 = blockIdx.x * 64;
    const int n0 = blockIdx.y * 64;
    const int tx = threadIdx.x & 63;
    const int ty = threadIdx.x >> 6;
    #pragma unroll
    for (int r = 0; r < 64; r += 4)
        tile[r + ty][tx] = f2bf(W1[(size_t)(k0 + r + ty) * HH_ + n0 + tx]);
    __syncthreads();
    #pragma unroll
    for (int r = 0; r < 64; r += 4)
        w1t[(size_t)(n0 + r + ty) * H_ + k0 + tx] = tile[tx][r + ty];
}

// ---------------- K1: span-mean pool, one WAVE per word. Staged loads forced by
// sched_barrier; clamp to span-end so duplicate rows hit L1 (no extra HBM lines).
__global__ __launch_bounds__(256) void k_pool(const float* __restrict__ enc,
                                              const int* __restrict__ starts,
                                              const int* __restrict__ ends,
                                              unsigned short* __restrict__ pooled,
                                              float* __restrict__ mask) {
    const int wave = threadIdx.x >> 6, lane = threadIdx.x & 63;
    const int gw = blockIdx.x * 4 + wave;            // word id
    const int s = starts[gw], e = ends[gw];
    const int len = e - s;                           // in [1,8] by construction
    const bool valid = (s < L_) && (e <= L_) && (s < e);
    floatx4 a0 = {0.f,0.f,0.f,0.f}, a1 = a0, a2 = a0;
    if (valid) {                                     // wave-uniform branch
        const int b = gw >> 9;
        const float* base = enc + ((size_t)b * L_ + s) * H_ + lane * 4;
        floatx4 v0[8], v1[8], v2[8];
        #pragma unroll
        for (int r = 0; r < 8; ++r) {                // 24 independent loads
            const int ro = ((r < len) ? r : (len - 1)) * H_;   // span-end clamp
            const floatx4* p = (const floatx4*)(base + ro);
            v0[r] = p[0]; v1[r] = p[64]; v2[r] = p[128];
        }
        __builtin_amdgcn_sched_barrier(0);           // loads may NOT sink past here
        const float inv = 1.0f / (float)len;
        #pragma unroll
        for (int r = 0; r < 8; ++r) {
            const float wr = (r < len) ? inv : 0.f;
            a0 += wr * v0[r]; a1 += wr * v1[r]; a2 += wr * v2[r];
        }
    }
    unsigned short* dst = pooled + (size_t)gw * H_ + lane * 4;
    ushort4 o;
    o.x=f2bf(a0[0]); o.y=f2bf(a0[1]); o.z=f2bf(a0[2]); o.w=f2bf(a0[3]); *(ushort4*)(dst)       = o;
    o.x=f2bf(a1[0]); o.y=f2bf(a1[1]); o.z=f2bf(a1[2]); o.w=f2bf(a1[3]); *(ushort4*)(dst + 256) = o;
    o.x=f2bf(a2[0]); o.y=f2bf(a2[1]); o.z=f2bf(a2[2]); o.w=f2bf(a2[3]); *(ushort4*)(dst + 512) = o;
    if (lane == 0) mask[gw] = valid ? 1.0f : 0.0f;
}

// ---------------- K2: GEMM1 [16384x768]@[768x384] bf16 MFMA + bias + exact GELU -> h fp32
#define G1_LDA 72
__global__ __launch_bounds__(512) void k_gemm1(const unsigned short* __restrict__ pooled,
                                               const unsigned short* __restrict__ w1t,
                                               const float* __restrict__ b1,
                                               float* __restrict__ h) {
    __shared__ unsigned short sA[64 * G1_LDA];       // 9216 B
    const int tid  = threadIdx.x;
    const int wave = tid >> 6, lane = tid & 63;
    const int wm = wave >> 2, wn = wave & 3;         // 2M x 4N waves
    const int lr = lane & 15, lk = lane >> 4;
    const int m0 = blockIdx.x * 64;

    floatx4 acc[2][6];
    #pragma unroll
    for (int i = 0; i < 2; ++i)
        #pragma unroll
        for (int j = 0; j < 6; ++j) acc[i][j] = {0.f,0.f,0.f,0.f};

    const int srow = tid >> 3;                       // 0..63
    const int sseg = (tid & 7) * 8;                  // 0..56 ushorts
    const unsigned short* bbase = w1t + (size_t)(wn * 96 + lr) * H_ + lk * 8;

    for (int kt = 0; kt < 12; ++kt) {
        const int k0 = kt * 64;
        // prefetch A for this tile before waiting on previous tile's readers
        bf16x8 av = *(const bf16x8*)(pooled + (size_t)(m0 + srow) * H_ + k0 + sseg);
        if (kt) __syncthreads();
        *(bf16x8*)(sA + srow * G1_LDA + sseg) = av;
        __syncthreads();
        #pragma unroll
        for (int kk = 0; kk < 2; ++kk) {
            bf16x8 af0 = *(const bf16x8*)(sA + (wm * 32 +  0 + lr) * G1_LDA + kk * 32 + lk * 8);
            bf16x8 af1 = *(const bf16x8*)(sA + (wm * 32 + 16 + lr) * G1_LDA + kk * 32 + lk * 8);
            bf16x8 bf[6];
            #pragma unroll
            for (int ni = 0; ni < 6; ++ni)
                bf[ni] = *(const bf16x8*)(bbase + (size_t)ni * 16 * H_ + k0 + kk * 32);
            #pragma unroll
            for (int ni = 0; ni < 6; ++ni) {
                acc[0][ni] = __builtin_amdgcn_mfma_f32_16x16x32_bf16(af0, bf[ni], acc[0][ni], 0, 0, 0);
                acc[1][ni] = __builtin_amdgcn_mfma_f32_16x16x32_bf16(af1, bf[ni], acc[1][ni], 0, 0, 0);
            }
        }
    }

    #pragma unroll
    for (int ni = 0; ni < 6; ++ni) {
        const int col = wn * 96 + ni * 16 + lr;
        const float bias = b1[col];
        #pragma unroll
        for (int mi = 0; mi < 2; ++mi) {
            #pragma unroll
            for (int r = 0; r < 4; ++r) {
                const int row = wm * 32 + mi * 16 + lk * 4 + r;
                const float x = acc[mi][ni][r] + bias;
                const float g = 0.5f * x * (1.0f + erff(x * 0.70710678118654752f));
                h[(size_t)(m0 + row) * HH_ + col] = g;
            }
        }
    }
}

// ---------------- K3: GEMM2 [16384x384]@[384x16] fp32 + bias -> logits
__global__ __launch_bounds__(256) void k_gemm2(const float* __restrict__ h,
                                               const float* __restrict__ W2,
                                               const float* __restrict__ b2,
                                               float* __restrict__ out) {
    __shared__ float sh[16 * 388];                   // padded rows: bank rotation 4
    __shared__ float sw[HH_ * NC_];                  // full W2
    const int tid = threadIdx.x;
    const int m0 = blockIdx.x * 16;
    const int r = tid >> 4, cseg = (tid & 15) * 4;
    #pragma unroll
    for (int j = 0; j < 6; ++j)
        *(float4*)(sh + r * 388 + cseg + j * 64) =
            *(const float4*)(h + (size_t)(m0 + r) * HH_ + cseg + j * 64);
    #pragma unroll
    for (int j = 0; j < 6; ++j) {
        const int idx = tid * 4 + j * 1024;
        *(float4*)(sw + idx) = *(const float4*)(W2 + idx);
    }
    __syncthreads();
    const int c = tid & 15;
    const float* hrow = sh + r * 388;
    float s0 = 0.f, s1 = 0.f, s2 = 0.f, s3 = 0.f;
    #pragma unroll 8
    for (int k = 0; k < HH_; k += 4) {
        const float4 hv = *(const float4*)(hrow + k);
        s0 += hv.x * sw[(k + 0) * NC_ + c];
        s1 += hv.y * sw[(k + 1) * NC_ + c];
        s2 += hv.z * sw[(k + 2) * NC_ + c];
        s3 += hv.w * sw[(k + 3) * NC_ + c];
    }
    out[(size_t)(m0 + r) * NC_ + c] = b2[c] + ((s0 + s1) + (s2 + s3));
}

extern "C" void kernel_launch(void* const* d_in, const int* in_sizes, int n_in,
                              void* d_out, int out_size, void* d_ws, size_t ws_size,
                              hipStream_t stream) {
    const float* enc    = (const float*)d_in[0];
    const int*   starts = (const int*)d_in[1];
    const int*   ends   = (const int*)d_in[2];
    const float* W1     = (const float*)d_in[3];
    const float* b1     = (const float*)d_in[4];
    const float* W2     = (const float*)d_in[5];
    const float* b2     = (const float*)d_in[6];
    float* out = (float*)d_out;

    unsigned short* w1t    = (unsigned short*)d_ws;                   // 384*768 bf16
    unsigned short* pooled = w1t + (size_t)HH_ * H_;                  // 16384*768 bf16
    float*          hbuf   = (float*)(pooled + (size_t)NWORDS * H_);  // 16384*384 f32
    float*          mask   = out + NLOGITS;

    hipLaunchKernelGGL(k_convert_w1, dim3(H_ / 64, HH_ / 64), dim3(256), 0, stream, W1, w1t);
    hipLaunchKernelGGL(k_pool, dim3(NWORDS / 4), dim3(256), 0, stream, enc, starts, ends, pooled, mask);
    hipLaunchKernelGGL(k_gemm1, dim3(NWORDS / 64), dim3(512), 0, stream, pooled, w1t, b1, hbuf);
    hipLaunchKernelGGL(k_gemm2, dim3(NWORDS / 16), dim3(256), 0, stream, hbuf, W2, b2, out);
}

// Round 6
// 335.504 us; speedup vs baseline: 1.0525x; 1.0525x over previous
//
#include <hip/hip_runtime.h>
#include <hip/hip_bf16.h>

#define B_   32
#define L_   2048
#define H_   768
#define W_   512
#define NC_  16
#define HH_  384                 // H/2
#define NWORDS (B_ * W_)         // 16384
#define NLOGITS (NWORDS * NC_)   // 262144

typedef __attribute__((ext_vector_type(8))) __bf16 bf16x8;
typedef __attribute__((ext_vector_type(4))) float floatx4;

static __device__ __forceinline__ unsigned short f2bf(float x) {
    union { float f; unsigned u; } v; v.f = x;
    unsigned r = v.u + 0x7FFF + ((v.u >> 16) & 1);   // RNE fp32->bf16
    return (unsigned short)(r >> 16);
}

// ---------------- K0: W1 [768][384] f32 -> w1t [384][768] bf16 (coalesced tiled transpose)
__global__ __launch_bounds__(256) void k_convert_w1(const float* __restrict__ W1,
                                                    unsigned short* __restrict__ w1t) {
    __shared__ unsigned short tile[64][65];
    const int k0 = blockIdx.x * 64;
    const int n0 = blockIdx.y * 64;
    const int tx = threadIdx.x & 63;
    const int ty = threadIdx.x >> 6;
    #pragma unroll
    for (int r = 0; r < 64; r += 4)
        tile[r + ty][tx] = f2bf(W1[(size_t)(k0 + r + ty) * HH_ + n0 + tx]);
    __syncthreads();
    #pragma unroll
    for (int r = 0; r < 64; r += 4)
        w1t[(size_t)(n0 + r + ty) * H_ + k0 + tx] = tile[tx][r + ty];
}

// ---------------- K1: span-mean pool, one WAVE per word (UNCHANGED from round 5).
__global__ __launch_bounds__(256) void k_pool(const float* __restrict__ enc,
                                              const int* __restrict__ starts,
                                              const int* __restrict__ ends,
                                              unsigned short* __restrict__ pooled,
                                              float* __restrict__ mask) {
    const int wave = threadIdx.x >> 6, lane = threadIdx.x & 63;
    const int gw = blockIdx.x * 4 + wave;            // word id
    const int s = starts[gw], e = ends[gw];
    const int len = e - s;                           // in [1,8] by construction
    const bool valid = (s < L_) && (e <= L_) && (s < e);
    floatx4 a0 = {0.f,0.f,0.f,0.f}, a1 = a0, a2 = a0;
    if (valid) {                                     // wave-uniform branch
        const int b = gw >> 9;
        const float* base = enc + ((size_t)b * L_ + s) * H_ + lane * 4;
        floatx4 v0[8], v1[8], v2[8];
        #pragma unroll
        for (int r = 0; r < 8; ++r) {                // 24 independent loads
            const int ro = ((r < len) ? r : (len - 1)) * H_;   // span-end clamp
            const floatx4* p = (const floatx4*)(base + ro);
            v0[r] = p[0]; v1[r] = p[64]; v2[r] = p[128];
        }
        __builtin_amdgcn_sched_barrier(0);           // loads may NOT sink past here
        const float inv = 1.0f / (float)len;
        #pragma unroll
        for (int r = 0; r < 8; ++r) {
            const float wr = (r < len) ? inv : 0.f;
            a0 += wr * v0[r]; a1 += wr * v1[r]; a2 += wr * v2[r];
        }
    }
    unsigned short* dst = pooled + (size_t)gw * H_ + lane * 4;
    ushort4 o;
    o.x=f2bf(a0[0]); o.y=f2bf(a0[1]); o.z=f2bf(a0[2]); o.w=f2bf(a0[3]); *(ushort4*)(dst)       = o;
    o.x=f2bf(a1[0]); o.y=f2bf(a1[1]); o.z=f2bf(a1[2]); o.w=f2bf(a1[3]); *(ushort4*)(dst + 256) = o;
    o.x=f2bf(a2[0]); o.y=f2bf(a2[1]); o.z=f2bf(a2[2]); o.w=f2bf(a2[3]); *(ushort4*)(dst + 512) = o;
    if (lane == 0) mask[gw] = valid ? 1.0f : 0.0f;
}

// ---------------- K2: fused MLP — GEMM1(bf16 MFMA) + GELU(h in LDS) + GEMM2 -> logits
#define BM   32
#define LDA  776                  // ushort stride: row rotation = 4 banks
#define LDH  388                  // float stride for h
__global__ __launch_bounds__(512) void k_mlp(const unsigned short* __restrict__ pooled,
                                             const unsigned short* __restrict__ w1t,
                                             const float* __restrict__ b1,
                                             const float* __restrict__ W2,
                                             const float* __restrict__ b2,
                                             float* __restrict__ out) {
    __shared__ float smem[BM * LDH];                  // 49,664 B: A-tile then h-tile
    __shared__ float swW2[HH_ * NC_];                 // 24,576 B
    unsigned short* sA = (unsigned short*)smem;       // [32][LDA] bf16

    const int tid  = threadIdx.x;
    const int wave = tid >> 6, lane = tid & 63;
    const int m0 = blockIdx.x * BM;

    // stage W2 -> LDS (12 floats per thread)
    #pragma unroll
    for (int j = 0; j < 3; ++j)
        *(float4*)(swW2 + tid * 4 + j * 2048) = *(const float4*)(W2 + tid * 4 + j * 2048);

    // stage A: 32 rows x 768 bf16; 16 threads per row, 6 bf16x8 each
    {
        const int row = tid >> 4, t16 = tid & 15;
        const unsigned short* src = pooled + (size_t)(m0 + row) * H_;
        unsigned short* dstrow = sA + row * LDA;
        #pragma unroll
        for (int j = 0; j < 6; ++j) {
            const int off = (t16 + 16 * j) * 8;
            *(bf16x8*)(dstrow + off) = *(const bf16x8*)(src + off);
        }
    }
    __syncthreads();

    // GEMM1: wave wn owns cols [wn*48, wn*48+48); B straight from L2-resident w1t
    const int lr = lane & 15, lk = lane >> 4;
    floatx4 acc[2][3];
    #pragma unroll
    for (int i = 0; i < 2; ++i)
        #pragma unroll
        for (int j = 0; j < 3; ++j) acc[i][j] = {0.f,0.f,0.f,0.f};

    const unsigned short* sa0 = sA + lr * LDA + lk * 8;
    const unsigned short* bp0 = w1t + (size_t)(wave * 48 +  0 + lr) * H_ + lk * 8;
    const unsigned short* bp1 = w1t + (size_t)(wave * 48 + 16 + lr) * H_ + lk * 8;
    const unsigned short* bp2 = w1t + (size_t)(wave * 48 + 32 + lr) * H_ + lk * 8;

    #pragma unroll
    for (int kk = 0; kk < 24; ++kk) {
        const int ko = kk * 32;
        bf16x8 af0 = *(const bf16x8*)(sa0 + ko);
        bf16x8 af1 = *(const bf16x8*)(sa0 + 16 * LDA + ko);
        bf16x8 bf0 = *(const bf16x8*)(bp0 + ko);
        bf16x8 bf1 = *(const bf16x8*)(bp1 + ko);
        bf16x8 bf2 = *(const bf16x8*)(bp2 + ko);
        acc[0][0] = __builtin_amdgcn_mfma_f32_16x16x32_bf16(af0, bf0, acc[0][0], 0, 0, 0);
        acc[1][0] = __builtin_amdgcn_mfma_f32_16x16x32_bf16(af1, bf0, acc[1][0], 0, 0, 0);
        acc[0][1] = __builtin_amdgcn_mfma_f32_16x16x32_bf16(af0, bf1, acc[0][1], 0, 0, 0);
        acc[1][1] = __builtin_amdgcn_mfma_f32_16x16x32_bf16(af1, bf1, acc[1][1], 0, 0, 0);
        acc[0][2] = __builtin_amdgcn_mfma_f32_16x16x32_bf16(af0, bf2, acc[0][2], 0, 0, 0);
        acc[1][2] = __builtin_amdgcn_mfma_f32_16x16x32_bf16(af1, bf2, acc[1][2], 0, 0, 0);
    }
    __syncthreads();   // all sA reads done; safe to overwrite with h

    // bias + exact GELU -> h fp32 in LDS [32][LDH]
    #pragma unroll
    for (int ni = 0; ni < 3; ++ni) {
        const int col = wave * 48 + ni * 16 + lr;
        const float bias = b1[col];
        #pragma unroll
        for (int mi = 0; mi < 2; ++mi) {
            #pragma unroll
            for (int r = 0; r < 4; ++r) {
                const int row = mi * 16 + lk * 4 + r;
                const float x = acc[mi][ni][r] + bias;
                const float g = 0.5f * x * (1.0f + erff(x * 0.70710678118654752f));
                smem[row * LDH + col] = g;
            }
        }
    }
    __syncthreads();

    // GEMM2: 32 rows x 16 classes; float4 h reads, W2 from LDS, 4 partial sums
    const int r = tid >> 4;
    const int c = tid & 15;
    const float* hrow = smem + r * LDH;
    float s0 = 0.f, s1 = 0.f, s2 = 0.f, s3 = 0.f;
    #pragma unroll 8
    for (int k = 0; k < HH_; k += 4) {
        const float4 hv = *(const float4*)(hrow + k);
        s0 += hv.x * swW2[(k + 0) * NC_ + c];
        s1 += hv.y * swW2[(k + 1) * NC_ + c];
        s2 += hv.z * swW2[(k + 2) * NC_ + c];
        s3 += hv.w * swW2[(k + 3) * NC_ + c];
    }
    out[(size_t)(m0 + r) * NC_ + c] = b2[c] + ((s0 + s1) + (s2 + s3));
}

extern "C" void kernel_launch(void* const* d_in, const int* in_sizes, int n_in,
                              void* d_out, int out_size, void* d_ws, size_t ws_size,
                              hipStream_t stream) {
    const float* enc    = (const float*)d_in[0];
    const int*   starts = (const int*)d_in[1];
    const int*   ends   = (const int*)d_in[2];
    const float* W1     = (const float*)d_in[3];
    const float* b1     = (const float*)d_in[4];
    const float* W2     = (const float*)d_in[5];
    const float* b2     = (const float*)d_in[6];
    float* out = (float*)d_out;

    unsigned short* w1t    = (unsigned short*)d_ws;                   // 384*768 bf16
    unsigned short* pooled = w1t + (size_t)HH_ * H_;                  // 16384*768 bf16
    float*          mask   = out + NLOGITS;

    hipLaunchKernelGGL(k_convert_w1, dim3(H_ / 64, HH_ / 64), dim3(256), 0, stream, W1, w1t);
    hipLaunchKernelGGL(k_pool, dim3(NWORDS / 4), dim3(256), 0, stream, enc, starts, ends, pooled, mask);
    hipLaunchKernelGGL(k_mlp, dim3(NWORDS / BM), dim3(512), 0, stream, pooled, w1t, b1, W2, b2, out);
}